// Round 10
// baseline (67.548 us; speedup 1.0000x reference)
//
#include <hip/hip_runtime.h>

#define DEV __device__ __forceinline__

DEV float rdlane(float v, int l) {
  return __int_as_float(__builtin_amdgcn_readlane(__float_as_int(v), l));
}
template <int CTRL>
DEV float dppmov(float v) {                   // pure-VALU lane move
  return __int_as_float(__builtin_amdgcn_update_dpp(
      0, __float_as_int(v), CTRL, 0xf, 0xf, true));
}
// xor-mask lane exchange: 1,2 = quad_perm DPP; 8 = row_ror:8 DPP;
// 4,16 = ds_swizzle immediate (within 32-lane group).
template <int M>
DEV float xorl(float v) {
  if constexpr (M == 1)       return dppmov<0xB1>(v);
  else if constexpr (M == 2)  return dppmov<0x4E>(v);
  else if constexpr (M == 8)  return dppmov<0x128>(v);
  else if constexpr (M == 4)
    return __int_as_float(__builtin_amdgcn_ds_swizzle(__float_as_int(v), 0x101F));
  else /* 16 */
    return __int_as_float(__builtin_amdgcn_ds_swizzle(__float_as_int(v), 0x401F));
}
// sin/cos(theta/2) via native v_sin_f32/v_cos_f32 (arg in revolutions)
DEV void sincos_half(float theta, float* s, float* c) {
  float rev = theta * 0.07957747154594767f;   // 1/(4*pi)
  *s = __builtin_amdgcn_sinf(rev);
  *c = __builtin_amdgcn_cosf(rev);
}

// One wave = TWO batch elements, one per 32-lane half (element = lane bit 5).
// Per lane: 8 complex amps (scalar re/im). Amp bits: lane b4..b0 = qubits 0..4,
// r bits 2,1,0 = qubits 5,6,7.
__global__ __launch_bounds__(256, 8) void qsim_kernel(const float* __restrict__ X,
                                                      const float* __restrict__ W,
                                                      float* __restrict__ out, int bs) {
  const int lane = threadIdx.x & 63;
  const int wave = blockIdx.x * (blockDim.x >> 6) + (threadIdx.x >> 6);
  const int b0 = wave * 2;
  if (b0 >= bs) return;

  // ---- weight sincos + HOISTED readlanes (32 SGPR-resident coefficients) ----
  float w = W[(((lane & 15) >> 3) << 4) + (lane & 7)];
  float sw_, cw_;
  sincos_half(w, &sw_, &cw_);
  float CG[16], SG[16];
#pragma unroll
  for (int g = 0; g < 16; ++g) { CG[g] = rdlane(cw_, g); SG[g] = rdlane(sw_, g); }

  // hoisted per-lane control-bit predicates
  const bool a4 = (lane >> 4) & 1, a3 = (lane >> 3) & 1, a2 = (lane >> 2) & 1,
             a1 = (lane >> 1) & 1, a0 = lane & 1;

  // ---- encoding chains: lane -> element (lane>>3)&1, qubit lane&7 ----
  const int ce = (lane >> 3) & 1;
  const int cq = lane & 7;
  int bb = b0 + ce; bb = bb >= bs ? bs - 1 : bb;
  const float* Xrow = X + (size_t)bb * 64;
  float ang[9];
#pragma unroll
  for (int i = 0; i < 9; ++i) {
    int idx = cq * 9 + i;                 // this chain's 9 angles are contiguous
    idx = idx > 63 ? 63 : idx;            // qubit 7 has only 1 rotation
    ang[i] = Xrow[idx];
  }
  const float Hc = 0.70710678118654752440f;
  float ar = Hc, ai = 0.f, br = Hc, bi = 0.f;   // column of (rotations*H)|0>
#pragma unroll
  for (int i = 0; i < 9; ++i) {
    float s, c;
    sincos_half(ang[i], &s, &c);
    if (i > 0) {                          // qubit-7 chain: identity after i=0
      bool dead = (cq == 7);
      c = dead ? 1.f : c;
      s = dead ? 0.f : s;
    }
    float nar, nai, nbr, nbi;
    if ((i & 1) == 0) {                   // RZ: A*=(c-is), B*=(c+is)
      nar = fmaf(ar, c,  ai * s);  nai = fmaf(ai, c, -ar * s);
      nbr = fmaf(br, c, -bi * s);  nbi = fmaf(bi, c,  br * s);
    } else {                              // RY
      nar = fmaf(c, ar, -s * br);  nai = fmaf(c, ai, -s * bi);
      nbr = fmaf(s, ar,  c * br);  nbi = fmaf(s, ai,  c * bi);
    }
    ar = nar; ai = nai; br = nbr; bi = nbi;
  }

  // publish chain results: (Ar,Ai,Br,Bi) per (element, qubit)
  __shared__ float4 ldsAB[4][16];
  const int wvid = (threadIdx.x >> 6) & 3;
  if (lane < 16) ldsAB[wvid][lane] = make_float4(ar, ai, br, bi);
  __builtin_amdgcn_wave_barrier();        // same-wave DS ordering fence

  // ---- build product-state amplitudes (my half's element) ----
  const int half = lane >> 5;
  const int base = half * 8;
  float Pr, Pi;
  {
    float4 F0 = ldsAB[wvid][base + 0];
    Pr = a4 ? F0.z : F0.x;  Pi = a4 ? F0.w : F0.y;
  }
#pragma unroll
  for (int q = 1; q <= 4; ++q) {
    float4 Fq = ldsAB[wvid][base + q];
    bool bit = (lane >> (4 - q)) & 1;
    float fr = bit ? Fq.z : Fq.x, fi = bit ? Fq.w : Fq.y;
    float nr = fmaf(Pr, fr, -Pi * fi);
    float ni = fmaf(Pr, fi,  Pi * fr);
    Pr = nr; Pi = ni;
  }
  float4 F5 = ldsAB[wvid][base + 5];
  float4 F6 = ldsAB[wvid][base + 6];
  float4 F7 = ldsAB[wvid][base + 7];
  float re[8], im[8];
  {
    float t0r = fmaf(Pr, F5.x, -Pi * F5.y), t0i = fmaf(Pr, F5.y, Pi * F5.x);
    float t1r = fmaf(Pr, F5.z, -Pi * F5.w), t1i = fmaf(Pr, F5.w, Pi * F5.z);
    float u00r = fmaf(t0r, F6.x, -t0i * F6.y), u00i = fmaf(t0r, F6.y, t0i * F6.x);
    float u01r = fmaf(t0r, F6.z, -t0i * F6.w), u01i = fmaf(t0r, F6.w, t0i * F6.z);
    float u10r = fmaf(t1r, F6.x, -t1i * F6.y), u10i = fmaf(t1r, F6.y, t1i * F6.x);
    float u11r = fmaf(t1r, F6.z, -t1i * F6.w), u11i = fmaf(t1r, F6.w, t1i * F6.z);
    re[0] = fmaf(u00r, F7.x, -u00i * F7.y); im[0] = fmaf(u00r, F7.y, u00i * F7.x);
    re[1] = fmaf(u00r, F7.z, -u00i * F7.w); im[1] = fmaf(u00r, F7.w, u00i * F7.z);
    re[2] = fmaf(u01r, F7.x, -u01i * F7.y); im[2] = fmaf(u01r, F7.y, u01i * F7.x);
    re[3] = fmaf(u01r, F7.z, -u01i * F7.w); im[3] = fmaf(u01r, F7.w, u01i * F7.z);
    re[4] = fmaf(u10r, F7.x, -u10i * F7.y); im[4] = fmaf(u10r, F7.y, u10i * F7.x);
    re[5] = fmaf(u10r, F7.z, -u10i * F7.w); im[5] = fmaf(u10r, F7.w, u10i * F7.z);
    re[6] = fmaf(u11r, F7.x, -u11i * F7.y); im[6] = fmaf(u11r, F7.y, u11i * F7.x);
    re[7] = fmaf(u11r, F7.z, -u11i * F7.w); im[7] = fmaf(u11r, F7.w, u11i * F7.z);
  }

  // ---- entangling: layer 0 CRX, layer 1 CRY; ctrl=q_i -> tgt=q_{i+1} ----
#define CRX_LANE(M, ACT, G) {                                     \
    float c1 = (ACT) ? CG[G] : 1.f;                               \
    float s1 = (ACT) ? SG[G] : 0.f;                               \
    _Pragma("unroll")                                             \
    for (int r = 0; r < 8; ++r) {                                 \
      float pre = xorl<M>(re[r]), pim = xorl<M>(im[r]);           \
      float nr = fmaf(s1, pim, c1 * re[r]);                       \
      float ni = fmaf(-s1, pre, c1 * im[r]);                      \
      re[r] = nr; im[r] = ni;                                     \
    } }
#define CRY_LANE(M, ACT, G) {                                     \
    float c1 = (ACT) ? CG[G] : 1.f;                               \
    float st = (lane & (M)) ? SG[G] : -SG[G];                     \
    float sp = (ACT) ? st : 0.f;                                  \
    _Pragma("unroll")                                             \
    for (int r = 0; r < 8; ++r) {                                 \
      float pre = xorl<M>(re[r]), pim = xorl<M>(im[r]);           \
      float nr = fmaf(sp, pre, c1 * re[r]);                       \
      float ni = fmaf(sp, pim, c1 * im[r]);                       \
      re[r] = nr; im[r] = ni;                                     \
    } }
#define CRX_M16_ODD(G) {                                          \
    float c1 = CG[G], s1 = SG[G];                                 \
    _Pragma("unroll")                                             \
    for (int r = 1; r < 8; r += 2) {                              \
      float pre = xorl<16>(re[r]), pim = xorl<16>(im[r]);         \
      float nr = fmaf(s1, pim, c1 * re[r]);                       \
      float ni = fmaf(-s1, pre, c1 * im[r]);                      \
      re[r] = nr; im[r] = ni;                                     \
    } }
#define CRY_M16_ODD(G) {                                          \
    float c1 = CG[G];                                             \
    float sp = (lane & 16) ? SG[G] : -SG[G];                      \
    _Pragma("unroll")                                             \
    for (int r = 1; r < 8; r += 2) {                              \
      float pre = xorl<16>(re[r]), pim = xorl<16>(im[r]);         \
      float nr = fmaf(sp, pre, c1 * re[r]);                       \
      float ni = fmaf(sp, pim, c1 * im[r]);                       \
      re[r] = nr; im[r] = ni;                                     \
    } }
#define PAIR_CRX(I, J, C1, S1) {                                  \
    float nIr = fmaf((S1), im[J], (C1) * re[I]);                  \
    float nIi = fmaf(-(S1), re[J], (C1) * im[I]);                 \
    float nJr = fmaf((S1), im[I], (C1) * re[J]);                  \
    float nJi = fmaf(-(S1), re[I], (C1) * im[J]);                 \
    re[I] = nIr; im[I] = nIi; re[J] = nJr; im[J] = nJi; }
#define PAIR_CRY(I, J, C1, S1) {                                  \
    float nIr = fmaf(-(S1), re[J], (C1) * re[I]);                 \
    float nIi = fmaf(-(S1), im[J], (C1) * im[I]);                 \
    float nJr = fmaf((S1), re[I], (C1) * re[J]);                  \
    float nJi = fmaf((S1), im[I], (C1) * im[J]);                  \
    re[I] = nIr; im[I] = nIi; re[J] = nJr; im[J] = nJi; }

  // ----- layer 0: CRX -----
  CRX_LANE(8,  a4, 0)                    // (q0->q1)
  CRX_LANE(4,  a3, 1)                    // (q1->q2)
  CRX_LANE(2,  a2, 2)                    // (q2->q3)
  CRX_LANE(1,  a1, 3)                    // (q3->q4)
  {                                      // (q4->q5): pairs (r, r+4), ctrl lane b0
    float c1 = a0 ? CG[4] : 1.f;
    float s1 = a0 ? SG[4] : 0.f;
    PAIR_CRX(0, 4, c1, s1) PAIR_CRX(1, 5, c1, s1)
    PAIR_CRX(2, 6, c1, s1) PAIR_CRX(3, 7, c1, s1)
  }
  PAIR_CRX(4, 6, CG[5], SG[5]) PAIR_CRX(5, 7, CG[5], SG[5])   // (q5->q6)
  PAIR_CRX(2, 3, CG[6], SG[6]) PAIR_CRX(6, 7, CG[6], SG[6])   // (q6->q7)
  CRX_M16_ODD(7)                         // (q7->q0)

  // ----- layer 1: CRY -----
  CRY_LANE(8,  a4, 8)
  CRY_LANE(4,  a3, 9)
  CRY_LANE(2,  a2, 10)
  CRY_LANE(1,  a1, 11)
  {
    float c1 = a0 ? CG[12] : 1.f;
    float s1 = a0 ? SG[12] : 0.f;
    PAIR_CRY(0, 4, c1, s1) PAIR_CRY(1, 5, c1, s1)
    PAIR_CRY(2, 6, c1, s1) PAIR_CRY(3, 7, c1, s1)
  }
  PAIR_CRY(4, 6, CG[13], SG[13]) PAIR_CRY(5, 7, CG[13], SG[13])
  PAIR_CRY(2, 3, CG[14], SG[14]) PAIR_CRY(6, 7, CG[14], SG[14])
  CRY_M16_ODD(15)

  // ---- measurement ----
  float p[8];
#pragma unroll
  for (int r = 0; r < 8; ++r) p[r] = fmaf(re[r], re[r], im[r] * im[r]);
  float s01 = p[0] + p[1], s23 = p[2] + p[3], s45 = p[4] + p[5], s67 = p[6] + p[7];
  float sL = s01 + s23, sH = s45 + s67;
  float wv = sL + sH;                    // WHT -> qubits 0..4 (lane bits)
  float d5 = sL - sH;                    // q5 (r bit2)
  float d6 = (s01 + s45) - (s23 + s67);  // q6 (r bit1)
  float d7 = (p[0] - p[1]) + (p[2] - p[3]) + (p[4] - p[5]) + (p[6] - p[7]); // q7

#define STAGE(K, M) {                                 \
    float pp = xorl<M>(wv);                           \
    wv = pp + (((lane >> K) & 1) ? -wv : wv);         \
    d5 += xorl<M>(d5);                                \
    d6 += xorl<M>(d6);                                \
    d7 += xorl<M>(d7);                                \
  }
  STAGE(0, 1) STAGE(1, 2) STAGE(2, 4) STAGE(3, 8) STAGE(4, 16)
#undef STAGE

  // ---- gather & store: each half writes its element's 8 outputs ----
  const int lpos = lane & 31;
  const int srcl = (lane & 32) + (16 >> lpos);   // q0..q4 sit in WHT lanes 16,8,4,2,1
  float g = __shfl(wv, srcl, 64);
  float val = (lpos == 5) ? d5 : (lpos == 6) ? d6 : (lpos == 7) ? d7 : g;
  const int brow = b0 + half;
  if (lpos < 8 && brow < bs) out[(size_t)brow * 8 + lpos] = val;
}

extern "C" void kernel_launch(void* const* d_in, const int* in_sizes, int n_in,
                              void* d_out, int out_size, void* d_ws, size_t ws_size,
                              hipStream_t stream) {
  const float* X = (const float*)d_in[0];   // (bs, 64) float32
  const float* W = (const float*)d_in[1];   // (2, 16) float32
  float* out = (float*)d_out;               // (bs, 8) float32
  int bs = in_sizes[0] / 64;
  int waves = (bs + 1) / 2;                 // 2 elements per wave
  const int waves_per_block = 4;
  const int threads = waves_per_block * 64;
  int blocks = (waves + waves_per_block - 1) / waves_per_block;
  hipLaunchKernelGGL(qsim_kernel, dim3(blocks), dim3(threads), 0, stream, X, W, out, bs);
}

// Round 11
// 66.694 us; speedup vs baseline: 1.0128x; 1.0128x over previous
//
#include <hip/hip_runtime.h>

#define DEV __device__ __forceinline__

DEV float rdlane(float v, int l) {
  return __int_as_float(__builtin_amdgcn_readlane(__float_as_int(v), l));
}
template <int CTRL>
DEV float dppmov(float v) {                   // pure-VALU lane move
  return __int_as_float(__builtin_amdgcn_update_dpp(
      0, __float_as_int(v), CTRL, 0xf, 0xf, true));
}
// xor-mask lane exchange: 1,2 = quad_perm DPP; 8 = row_ror:8 DPP;
// 4,16 = ds_swizzle immediate (within 32-lane group).
template <int M>
DEV float xorl(float v) {
  if constexpr (M == 1)       return dppmov<0xB1>(v);
  else if constexpr (M == 2)  return dppmov<0x4E>(v);
  else if constexpr (M == 8)  return dppmov<0x128>(v);
  else if constexpr (M == 4)
    return __int_as_float(__builtin_amdgcn_ds_swizzle(__float_as_int(v), 0x101F));
  else /* 16 */
    return __int_as_float(__builtin_amdgcn_ds_swizzle(__float_as_int(v), 0x401F));
}
// sin/cos(theta/2) via native v_sin_f32/v_cos_f32 (arg in revolutions)
DEV void sincos_half(float theta, float* s, float* c) {
  float rev = theta * 0.07957747154594767f;   // 1/(4*pi)
  *s = __builtin_amdgcn_sinf(rev);
  *c = __builtin_amdgcn_cosf(rev);
}

// One wave = TWO batch elements, one per 32-lane half (element = lane bit 5).
// Per lane: 8 complex amps (scalar re/im). Amp bits: lane b4..b0 = qubits 0..4,
// r bits 2,1,0 = qubits 5,6,7.
// NOTE: plain __launch_bounds__(256) — forcing 8 waves/EU (<=64 VGPR) causes
// scratch spills that dominated runtime in R5..R10.
__global__ __launch_bounds__(256) void qsim_kernel(const float* __restrict__ X,
                                                   const float* __restrict__ W,
                                                   float* __restrict__ out, int bs) {
  const int lane = threadIdx.x & 63;
  const int wave = blockIdx.x * (blockDim.x >> 6) + (threadIdx.x >> 6);
  const int b0 = wave * 2;
  if (b0 >= bs) return;

  // ---- weight sincos: lane g<16 holds gate g = l*8+i -> W[l*16+i] ----
  float w = W[(((lane & 15) >> 3) << 4) + (lane & 7)];
  float sw_, cw_;
  sincos_half(w, &sw_, &cw_);

  // per-lane control-bit predicates
  const bool a4 = (lane >> 4) & 1, a3 = (lane >> 3) & 1, a2 = (lane >> 2) & 1,
             a1 = (lane >> 1) & 1, a0 = lane & 1;

  // ---- encoding chains: lane -> element (lane>>3)&1, qubit lane&7 ----
  const int ce = (lane >> 3) & 1;
  const int cq = lane & 7;
  int bb = b0 + ce; bb = bb >= bs ? bs - 1 : bb;
  const float* Xrow = X + (size_t)bb * 64;
  float ang[9];
#pragma unroll
  for (int i = 0; i < 9; ++i) {
    int idx = cq * 9 + i;                 // this chain's 9 angles are contiguous
    idx = idx > 63 ? 63 : idx;            // qubit 7 has only 1 rotation
    ang[i] = Xrow[idx];
  }
  const float Hc = 0.70710678118654752440f;
  float ar = Hc, ai = 0.f, br = Hc, bi = 0.f;   // column of (rotations*H)|0>
#pragma unroll
  for (int i = 0; i < 9; ++i) {
    float s, c;
    sincos_half(ang[i], &s, &c);
    if (i > 0) {                          // qubit-7 chain: identity after i=0
      bool dead = (cq == 7);
      c = dead ? 1.f : c;
      s = dead ? 0.f : s;
    }
    float nar, nai, nbr, nbi;
    if ((i & 1) == 0) {                   // RZ: A*=(c-is), B*=(c+is)
      nar = fmaf(ar, c,  ai * s);  nai = fmaf(ai, c, -ar * s);
      nbr = fmaf(br, c, -bi * s);  nbi = fmaf(bi, c,  br * s);
    } else {                              // RY
      nar = fmaf(c, ar, -s * br);  nai = fmaf(c, ai, -s * bi);
      nbr = fmaf(s, ar,  c * br);  nbi = fmaf(s, ai,  c * bi);
    }
    ar = nar; ai = nai; br = nbr; bi = nbi;
  }

  // publish chain results: (Ar,Ai,Br,Bi) per (element, qubit)
  __shared__ float4 ldsAB[4][16];
  const int wvid = (threadIdx.x >> 6) & 3;
  if (lane < 16) ldsAB[wvid][lane] = make_float4(ar, ai, br, bi);
  __builtin_amdgcn_wave_barrier();        // same-wave DS ordering fence

  // ---- build product-state amplitudes (my half's element) ----
  const int half = lane >> 5;
  const int base = half * 8;
  float Pr, Pi;
  {
    float4 F0 = ldsAB[wvid][base + 0];
    Pr = a4 ? F0.z : F0.x;  Pi = a4 ? F0.w : F0.y;
  }
#pragma unroll
  for (int q = 1; q <= 4; ++q) {
    float4 Fq = ldsAB[wvid][base + q];
    bool bit = (lane >> (4 - q)) & 1;
    float fr = bit ? Fq.z : Fq.x, fi = bit ? Fq.w : Fq.y;
    float nr = fmaf(Pr, fr, -Pi * fi);
    float ni = fmaf(Pr, fi,  Pi * fr);
    Pr = nr; Pi = ni;
  }
  float4 F5 = ldsAB[wvid][base + 5];
  float4 F6 = ldsAB[wvid][base + 6];
  float4 F7 = ldsAB[wvid][base + 7];
  float re[8], im[8];
  {
    float t0r = fmaf(Pr, F5.x, -Pi * F5.y), t0i = fmaf(Pr, F5.y, Pi * F5.x);
    float t1r = fmaf(Pr, F5.z, -Pi * F5.w), t1i = fmaf(Pr, F5.w, Pi * F5.z);
    float u00r = fmaf(t0r, F6.x, -t0i * F6.y), u00i = fmaf(t0r, F6.y, t0i * F6.x);
    float u01r = fmaf(t0r, F6.z, -t0i * F6.w), u01i = fmaf(t0r, F6.w, t0i * F6.z);
    float u10r = fmaf(t1r, F6.x, -t1i * F6.y), u10i = fmaf(t1r, F6.y, t1i * F6.x);
    float u11r = fmaf(t1r, F6.z, -t1i * F6.w), u11i = fmaf(t1r, F6.w, t1i * F6.z);
    re[0] = fmaf(u00r, F7.x, -u00i * F7.y); im[0] = fmaf(u00r, F7.y, u00i * F7.x);
    re[1] = fmaf(u00r, F7.z, -u00i * F7.w); im[1] = fmaf(u00r, F7.w, u00i * F7.z);
    re[2] = fmaf(u01r, F7.x, -u01i * F7.y); im[2] = fmaf(u01r, F7.y, u01i * F7.x);
    re[3] = fmaf(u01r, F7.z, -u01i * F7.w); im[3] = fmaf(u01r, F7.w, u01i * F7.z);
    re[4] = fmaf(u10r, F7.x, -u10i * F7.y); im[4] = fmaf(u10r, F7.y, u10i * F7.x);
    re[5] = fmaf(u10r, F7.z, -u10i * F7.w); im[5] = fmaf(u10r, F7.w, u10i * F7.z);
    re[6] = fmaf(u11r, F7.x, -u11i * F7.y); im[6] = fmaf(u11r, F7.y, u11i * F7.x);
    re[7] = fmaf(u11r, F7.z, -u11i * F7.w); im[7] = fmaf(u11r, F7.w, u11i * F7.z);
  }

  // ---- entangling: layer 0 CRX, layer 1 CRY; ctrl=q_i -> tgt=q_{i+1} ----
  // coefficients fetched inline (<=2 live at a time; readlane -> SGPR)
#define CRX_LANE(M, ACT, G) {                                     \
    float cg = rdlane(cw_, G), sg = rdlane(sw_, G);               \
    float c1 = (ACT) ? cg : 1.f;                                  \
    float s1 = (ACT) ? sg : 0.f;                                  \
    _Pragma("unroll")                                             \
    for (int r = 0; r < 8; ++r) {                                 \
      float pre = xorl<M>(re[r]), pim = xorl<M>(im[r]);           \
      float nr = fmaf(s1, pim, c1 * re[r]);                       \
      float ni = fmaf(-s1, pre, c1 * im[r]);                      \
      re[r] = nr; im[r] = ni;                                     \
    } }
#define CRY_LANE(M, ACT, G) {                                     \
    float cg = rdlane(cw_, G), sg = rdlane(sw_, G);               \
    float c1 = (ACT) ? cg : 1.f;                                  \
    float st = (lane & (M)) ? sg : -sg;                           \
    float sp = (ACT) ? st : 0.f;                                  \
    _Pragma("unroll")                                             \
    for (int r = 0; r < 8; ++r) {                                 \
      float pre = xorl<M>(re[r]), pim = xorl<M>(im[r]);           \
      float nr = fmaf(sp, pre, c1 * re[r]);                       \
      float ni = fmaf(sp, pim, c1 * im[r]);                       \
      re[r] = nr; im[r] = ni;                                     \
    } }
#define CRX_M16_ODD(G) {                                          \
    float c1 = rdlane(cw_, G), s1 = rdlane(sw_, G);               \
    _Pragma("unroll")                                             \
    for (int r = 1; r < 8; r += 2) {                              \
      float pre = xorl<16>(re[r]), pim = xorl<16>(im[r]);         \
      float nr = fmaf(s1, pim, c1 * re[r]);                       \
      float ni = fmaf(-s1, pre, c1 * im[r]);                      \
      re[r] = nr; im[r] = ni;                                     \
    } }
#define CRY_M16_ODD(G) {                                          \
    float c1 = rdlane(cw_, G);                                    \
    float sg = rdlane(sw_, G);                                    \
    float sp = (lane & 16) ? sg : -sg;                            \
    _Pragma("unroll")                                             \
    for (int r = 1; r < 8; r += 2) {                              \
      float pre = xorl<16>(re[r]), pim = xorl<16>(im[r]);         \
      float nr = fmaf(sp, pre, c1 * re[r]);                       \
      float ni = fmaf(sp, pim, c1 * im[r]);                       \
      re[r] = nr; im[r] = ni;                                     \
    } }
#define PAIR_CRX(I, J, C1, S1) {                                  \
    float nIr = fmaf((S1), im[J], (C1) * re[I]);                  \
    float nIi = fmaf(-(S1), re[J], (C1) * im[I]);                 \
    float nJr = fmaf((S1), im[I], (C1) * re[J]);                  \
    float nJi = fmaf(-(S1), re[I], (C1) * im[J]);                 \
    re[I] = nIr; im[I] = nIi; re[J] = nJr; im[J] = nJi; }
#define PAIR_CRY(I, J, C1, S1) {                                  \
    float nIr = fmaf(-(S1), re[J], (C1) * re[I]);                 \
    float nIi = fmaf(-(S1), im[J], (C1) * im[I]);                 \
    float nJr = fmaf((S1), re[I], (C1) * re[J]);                  \
    float nJi = fmaf((S1), im[I], (C1) * im[J]);                  \
    re[I] = nIr; im[I] = nIi; re[J] = nJr; im[J] = nJi; }

  // ----- layer 0: CRX -----
  CRX_LANE(8,  a4, 0)                    // (q0->q1)
  CRX_LANE(4,  a3, 1)                    // (q1->q2)
  CRX_LANE(2,  a2, 2)                    // (q2->q3)
  CRX_LANE(1,  a1, 3)                    // (q3->q4)
  {                                      // (q4->q5): pairs (r, r+4), ctrl lane b0
    float cg = rdlane(cw_, 4), sg = rdlane(sw_, 4);
    float c1 = a0 ? cg : 1.f;
    float s1 = a0 ? sg : 0.f;
    PAIR_CRX(0, 4, c1, s1) PAIR_CRX(1, 5, c1, s1)
    PAIR_CRX(2, 6, c1, s1) PAIR_CRX(3, 7, c1, s1)
  }
  {                                      // (q5->q6)
    float cg = rdlane(cw_, 5), sg = rdlane(sw_, 5);
    PAIR_CRX(4, 6, cg, sg) PAIR_CRX(5, 7, cg, sg)
  }
  {                                      // (q6->q7)
    float cg = rdlane(cw_, 6), sg = rdlane(sw_, 6);
    PAIR_CRX(2, 3, cg, sg) PAIR_CRX(6, 7, cg, sg)
  }
  CRX_M16_ODD(7)                         // (q7->q0)

  // ----- layer 1: CRY -----
  CRY_LANE(8,  a4, 8)
  CRY_LANE(4,  a3, 9)
  CRY_LANE(2,  a2, 10)
  CRY_LANE(1,  a1, 11)
  {
    float cg = rdlane(cw_, 12), sg = rdlane(sw_, 12);
    float c1 = a0 ? cg : 1.f;
    float s1 = a0 ? sg : 0.f;
    PAIR_CRY(0, 4, c1, s1) PAIR_CRY(1, 5, c1, s1)
    PAIR_CRY(2, 6, c1, s1) PAIR_CRY(3, 7, c1, s1)
  }
  {
    float cg = rdlane(cw_, 13), sg = rdlane(sw_, 13);
    PAIR_CRY(4, 6, cg, sg) PAIR_CRY(5, 7, cg, sg)
  }
  {
    float cg = rdlane(cw_, 14), sg = rdlane(sw_, 14);
    PAIR_CRY(2, 3, cg, sg) PAIR_CRY(6, 7, cg, sg)
  }
  CRY_M16_ODD(15)

  // ---- measurement ----
  float p[8];
#pragma unroll
  for (int r = 0; r < 8; ++r) p[r] = fmaf(re[r], re[r], im[r] * im[r]);
  float s01 = p[0] + p[1], s23 = p[2] + p[3], s45 = p[4] + p[5], s67 = p[6] + p[7];
  float sL = s01 + s23, sH = s45 + s67;
  float wv = sL + sH;                    // WHT -> qubits 0..4 (lane bits)
  float d5 = sL - sH;                    // q5 (r bit2)
  float d6 = (s01 + s45) - (s23 + s67);  // q6 (r bit1)
  float d7 = (p[0] - p[1]) + (p[2] - p[3]) + (p[4] - p[5]) + (p[6] - p[7]); // q7

#define STAGE(K, M) {                                 \
    float pp = xorl<M>(wv);                           \
    wv = pp + (((lane >> K) & 1) ? -wv : wv);         \
    d5 += xorl<M>(d5);                                \
    d6 += xorl<M>(d6);                                \
    d7 += xorl<M>(d7);                                \
  }
  STAGE(0, 1) STAGE(1, 2) STAGE(2, 4) STAGE(3, 8) STAGE(4, 16)
#undef STAGE

  // ---- gather & store: each half writes its element's 8 outputs ----
  const int lpos = lane & 31;
  const int srcl = (lane & 32) + (16 >> lpos);   // q0..q4 sit in WHT lanes 16,8,4,2,1
  float g = __shfl(wv, srcl, 64);
  float val = (lpos == 5) ? d5 : (lpos == 6) ? d6 : (lpos == 7) ? d7 : g;
  const int brow = b0 + half;
  if (lpos < 8 && brow < bs) out[(size_t)brow * 8 + lpos] = val;
}

extern "C" void kernel_launch(void* const* d_in, const int* in_sizes, int n_in,
                              void* d_out, int out_size, void* d_ws, size_t ws_size,
                              hipStream_t stream) {
  const float* X = (const float*)d_in[0];   // (bs, 64) float32
  const float* W = (const float*)d_in[1];   // (2, 16) float32
  float* out = (float*)d_out;               // (bs, 8) float32
  int bs = in_sizes[0] / 64;
  int waves = (bs + 1) / 2;                 // 2 elements per wave
  const int waves_per_block = 4;
  const int threads = waves_per_block * 64;
  int blocks = (waves + waves_per_block - 1) / waves_per_block;
  hipLaunchKernelGGL(qsim_kernel, dim3(blocks), dim3(threads), 0, stream, X, W, out, bs);
}